// Round 17
// baseline (659.775 us; speedup 1.0000x reference)
//
#include <hip/hip_runtime.h>
#include <hip/hip_bf16.h>

// LocalCrossAttentionBlock3D — R17: ZERO-BARRIER k_attn/k_ffn. Weights read
// directly from global (lane-major coalesced frags, L2-resident); all compute
// wave-local; waves fully independent. B=2,C=96,D=H=W=48,NH=4,dh=24,HID=384.

#define G_TOK 221184
#define TOK_PER_B 110592
#define STREAM_ELEMS 21233664  // G_TOK*96

typedef __attribute__((ext_vector_type(8))) short short8;
typedef __attribute__((ext_vector_type(4))) float f32x4;
typedef unsigned short ushort_t;
typedef unsigned int uint_t;

#define MFMA16 __builtin_amdgcn_mfma_f32_16x16x32_bf16

__device__ __forceinline__ float gelu_erf(float x) {
    return 0.5f * x * (1.0f + erff(x * 0.70710678118654752f));
}
__device__ __forceinline__ float gelu_tanh(float x) {
    float u = x * (1.5957691216f + 0.0713548163f * x * x);
    return x / (1.0f + __expf(-u));
}
__device__ __forceinline__ ushort_t bfb(float f) {
    __hip_bfloat16 h = __float2bfloat16(f);
    return *reinterpret_cast<ushort_t*>(&h);
}
__device__ __forceinline__ void unpack8(uint4 v, float* o) {
    o[0] = __uint_as_float(v.x << 16); o[1] = __uint_as_float(v.x & 0xffff0000u);
    o[2] = __uint_as_float(v.y << 16); o[3] = __uint_as_float(v.y & 0xffff0000u);
    o[4] = __uint_as_float(v.z << 16); o[5] = __uint_as_float(v.z & 0xffff0000u);
    o[6] = __uint_as_float(v.w << 16); o[7] = __uint_as_float(v.w & 0xffff0000u);
}
__device__ __forceinline__ uint4 pack8(const float* f) {
    uint4 v;
    v.x = (uint_t)bfb(f[0]) | ((uint_t)bfb(f[1]) << 16);
    v.y = (uint_t)bfb(f[2]) | ((uint_t)bfb(f[3]) << 16);
    v.z = (uint_t)bfb(f[4]) | ((uint_t)bfb(f[5]) << 16);
    v.w = (uint_t)bfb(f[6]) | ((uint_t)bfb(f[7]) << 16);
    return v;
}
__device__ __forceinline__ uint2 pack4(const float* f) {
    uint2 v;
    v.x = (uint_t)bfb(f[0]) | ((uint_t)bfb(f[1]) << 16);
    v.y = (uint_t)bfb(f[2]) | ((uint_t)bfb(f[3]) << 16);
    return v;
}
__device__ __forceinline__ short8 pks8(const float* f) {
    short8 r;
    #pragma unroll
    for (int j = 0; j < 8; ++j) r[j] = (short)bfb(f[j]);
    return r;
}

// ---------------------------------------------------------------------------
// K0: fold LN affines into LANE-MAJOR fragment bf16 weights.
__global__ __launch_bounds__(256) void k_fold(
    const float* __restrict__ Wi, const float* __restrict__ bi,
    const float* __restrict__ Wo, const float* __restrict__ bo,
    const float* __restrict__ W1, const float* __restrict__ b1,
    const float* __restrict__ W2, const float* __restrict__ b2,
    const float* __restrict__ Wc,
    const float* __restrict__ qnw, const float* __restrict__ qnb,
    const float* __restrict__ kvw, const float* __restrict__ kvb,
    const float* __restrict__ fnw, const float* __restrict__ fnb,
    ushort_t* __restrict__ w, float* __restrict__ bs)
{
    const float scale = 0.20412414523193150f;  // 1/sqrt(24)
    int tid0 = blockIdx.x * 256 + threadIdx.x;
    int nth = gridDim.x * 256;
    for (int o = tid0; o < 120672; o += nth) {
        if (o < 36864) {
            int blkid = o / 9216, oo = o % 9216;
            int e = oo & 7, ln = (oo >> 3) & 63, g = oo >> 9;
            int t = g / 3, u = g % 3, l15 = ln & 15, kb = ln >> 4;
            int c = t * 16 + l15, k = u * 32 + kb * 8 + e;
            float v;
            if (blkid == 0)      v = Wi[c * 96 + k] * qnw[k] * scale;
            else if (blkid == 1) v = Wi[(96 + c) * 96 + k] * kvw[k];
            else if (blkid == 2) v = Wi[(192 + c) * 96 + k] * kvw[k];
            else                 v = Wo[c * 96 + k];
            w[o] = bfb(v);
        } else if (o < 110592) {
            int oo = o - 36864; int half = oo / 36864; oo %= 36864;
            int e = oo & 7, ln = (oo >> 3) & 63, g = oo >> 9;
            int ch = g / 18, r = g % 18, tt = r / 3, u = r % 3;
            int l15 = ln & 15, kb = ln >> 4;
            float v;
            if (half == 0) {
                int c = ch * 96 + tt * 16 + l15, k = u * 32 + kb * 8 + e;
                v = W1[c * 96 + k] * fnw[k];
            } else {
                int c = tt * 16 + l15, k = ch * 96 + u * 32 + kb * 8 + e;
                v = W2[c * 384 + k];
            }
            w[o] = bfb(v);
        } else if (o < 119808) {
            int oo = o - 110592;
            int e = oo & 7, ln = (oo >> 3) & 63, g = oo >> 9;
            int t = g / 3, u = g % 3, l15 = ln & 15, kb = ln >> 4;
            w[o] = bfb(Wc[(t * 16 + l15) * 96 + u * 32 + kb * 8 + e]);
        } else {
            int x = o - 119808;
            if (x < 96) {
                float s = bi[x];
                #pragma unroll 4
                for (int k = 0; k < 96; ++k) s += qnb[k] * Wi[x * 96 + k];
                bs[x] = s * scale;
            } else if (x < 192) {
                int c = x - 96; float s = bi[96 + c];
                #pragma unroll 4
                for (int k = 0; k < 96; ++k) s += kvb[k] * Wi[(96 + c) * 96 + k];
                bs[x] = s;
            } else if (x < 288) {
                int c = x - 192; float s = bi[192 + c];
                #pragma unroll 4
                for (int k = 0; k < 96; ++k) s += kvb[k] * Wi[(192 + c) * 96 + k];
                bs[x] = s;
            } else if (x < 384) {
                bs[x] = bo[x - 288];
            } else if (x < 768) {
                int c = x - 384; float s = b1[c];
                #pragma unroll 4
                for (int k = 0; k < 96; ++k) s += fnb[k] * W1[c * 96 + k];
                bs[x] = s;
            } else {
                bs[x] = b2[x - 768];
            }
        }
    }
}

// ---------------------------------------------------------------------------
// K1: gather [B,C,D,H,W] f32 -> token-major bf16 X[G,96].
__global__ __launch_bounds__(256) void k_gather(
    const float* __restrict__ srcf, const float* __restrict__ srcb,
    ushort_t* __restrict__ Xf, ushort_t* __restrict__ Xb)
{
    __shared__ float tile[192 * 97];
    int blk = blockIdx.x;
    const float* src; ushort_t* X;
    if (blk < 1152) { src = srcf; X = Xf; }
    else            { src = srcb; X = Xb; blk -= 1152; }
    int b = blk / 576, rem = blk % 576, dw = rem / 24, hw = rem % 24;
    int tid = threadIdx.x;
    for (int i = tid; i < 384 * 48; i += 256) {
        int r = i / 48, w = i % 48;
        int c = r >> 2, d_off = (r >> 1) & 1, h_off = r & 1;
        float v = src[((((long)b * 96 + c) * 48 + dw * 2 + d_off) * 48 + hw * 2 + h_off) * 48 + w];
        int t = (w >> 1) * 8 + d_off * 4 + h_off * 2 + (w & 1);
        tile[t * 97 + c] = v;
    }
    __syncthreads();
    long base = ((((long)b * 24 + dw) * 24 + hw) * 24) * 8;
    for (int i = tid; i < 192 * 12; i += 256) {
        int t = i / 12, c8 = i % 12;
        *(uint4*)&X[(base + t) * 96 + c8 * 8] = pack8(&tile[t * 97 + c8 * 8]);
    }
}

// ---------------------------------------------------------------------------
// Transposed wave-local GEMM (lane-major frags, W from GLOBAL): D^T = W x X.
__device__ __forceinline__ void gemmT_stage(
    const short8* xb2, const ushort_t* __restrict__ W,
    const float* __restrict__ bias, ushort_t* outs,
    int mbase, int l15, int kb)
{
    const int ln8 = (kb * 16 + l15) * 8;
    #pragma unroll
    for (int t = 0; t < 6; ++t) {
        float4 bv = *(const float4*)&bias[t * 16 + kb * 4];
        f32x4 A0 = {bv.x, bv.y, bv.z, bv.w};
        f32x4 A1 = {bv.x, bv.y, bv.z, bv.w};
        #pragma unroll
        for (int u = 0; u < 3; ++u) {
            short8 bw = *(const short8*)&W[(t * 3 + u) * 512 + ln8];
            A0 = MFMA16(bw, xb2[u],     A0, 0, 0, 0);
            A1 = MFMA16(bw, xb2[3 + u], A1, 0, 0, 0);
        }
        float f0[4], f1[4];
        #pragma unroll
        for (int i = 0; i < 4; ++i) { f0[i] = A0[i]; f1[i] = A1[i]; }
        *(uint2*)&outs[(mbase + l15) * 104 + t * 16 + kb * 4]      = pack4(f0);
        *(uint2*)&outs[(mbase + 16 + l15) * 104 + t * 16 + kb * 4] = pack4(f1);
    }
}

// K2: fused cross-MHA, ZERO barriers, all weights global. (256,2). grid 1728.
__global__ __launch_bounds__(256, 2) void k_attn(
    ushort_t* __restrict__ Xf, ushort_t* __restrict__ Xb,
    const ushort_t* __restrict__ wf, const ushort_t* __restrict__ wb,
    const float* __restrict__ bsf, const float* __restrict__ bsb)
{
    __shared__ ushort_t qs[128 * 104];
    __shared__ ushort_t kv[128 * 104];
    int tid = threadIdx.x, lane = tid & 63, wv = tid >> 6, mbase = wv * 32;
    int l15 = lane & 15, kb = lane >> 4;
    long g0 = (long)blockIdx.x * 128;

    short8 fr[2][6];
    #pragma unroll
    for (int s = 0; s < 2; ++s) {
        #pragma unroll
        for (int m = 0; m < 2; ++m) {
            const ushort_t* px = (s ? Xb : Xf) + (g0 + mbase + m * 16 + l15) * 96 + kb * 8;
            float f[24];
            unpack8(*(const uint4*)px, f);
            unpack8(*(const uint4*)(px + 32), f + 8);
            unpack8(*(const uint4*)(px + 64), f + 16);
            float s1 = 0.f, s2 = 0.f;
            #pragma unroll
            for (int j = 0; j < 24; ++j) { s1 += f[j]; s2 += f[j] * f[j]; }
            s1 += __shfl_xor(s1, 16); s1 += __shfl_xor(s1, 32);
            s2 += __shfl_xor(s2, 16); s2 += __shfl_xor(s2, 32);
            float mm = s1 * (1.f / 96.f);
            float rr = rsqrtf(s2 * (1.f / 96.f) - mm * mm + 1e-5f);
            #pragma unroll
            for (int j = 0; j < 24; ++j) f[j] = (f[j] - mm) * rr;
            fr[s][m * 3 + 0] = pks8(f);
            fr[s][m * 3 + 1] = pks8(f + 8);
            fr[s][m * 3 + 2] = pks8(f + 16);
        }
    }

    #pragma unroll
    for (int dir = 0; dir < 2; ++dir) {
        const ushort_t* W = dir ? wb : wf;
        const float* bs = dir ? bsb : bsf;
        ushort_t* X = dir ? Xb : Xf;

        gemmT_stage(fr[dir],     W,        bs,      qs, mbase, l15, kb);  // Q
        gemmT_stage(fr[dir ^ 1], W + 9216, bs + 96, kv, mbase, l15, kb);  // K

        // scores — all rows wave-local, no barrier
        float sc[2][8], inv[2];
        #pragma unroll
        for (int it = 0; it < 2; ++it) {
            int idx = lane + 64 * it;
            int win = (idx >> 5) & 3, hd = (idx >> 3) & 3, q8 = idx & 7;
            int tq = mbase + win * 8 + q8, ko = hd * 24;
            float qf[24];
            #pragma unroll
            for (int u = 0; u < 3; ++u)
                unpack8(*(const uint4*)&qs[tq * 104 + ko + u * 8], qf + u * 8);
            float mx = -1e30f;
            #pragma unroll
            for (int j = 0; j < 8; ++j) {
                float s = 0.f;
                #pragma unroll
                for (int u = 0; u < 3; ++u) {
                    float kf[8];
                    unpack8(*(const uint4*)&kv[(mbase + win * 8 + j) * 104 + ko + u * 8], kf);
                    #pragma unroll
                    for (int d = 0; d < 8; ++d) s += qf[u * 8 + d] * kf[d];
                }
                sc[it][j] = s; mx = fmaxf(mx, s);
            }
            float sum = 0.f;
            #pragma unroll
            for (int j = 0; j < 8; ++j) { sc[it][j] = __expf(sc[it][j] - mx); sum += sc[it][j]; }
            inv[it] = 1.f / sum;
        }

        gemmT_stage(fr[dir ^ 1], W + 18432, bs + 192, kv, mbase, l15, kb);  // V over K

        // O = P.V -> qs, per-u 8-wide accumulation
        #pragma unroll
        for (int it = 0; it < 2; ++it) {
            int idx = lane + 64 * it;
            int win = (idx >> 5) & 3, hd = (idx >> 3) & 3, q8 = idx & 7;
            int tq = mbase + win * 8 + q8, ko = hd * 24;
            #pragma unroll
            for (int u = 0; u < 3; ++u) {
                float of8[8];
                #pragma unroll
                for (int d = 0; d < 8; ++d) of8[d] = 0.f;
                #pragma unroll
                for (int j = 0; j < 8; ++j) {
                    float vf[8];
                    unpack8(*(const uint4*)&kv[(mbase + win * 8 + j) * 104 + ko + u * 8], vf);
                    #pragma unroll
                    for (int d = 0; d < 8; ++d) of8[d] += sc[it][j] * vf[d];
                }
                #pragma unroll
                for (int d = 0; d < 8; ++d) of8[d] *= inv[it];
                *(uint4*)&qs[tq * 104 + ko + u * 8] = pack8(of8);
            }
        }

        // out-proj (global Wo): frags from qs, D staged back into qs
        {
            short8 o0[6];
            #pragma unroll
            for (int m = 0; m < 2; ++m)
                #pragma unroll
                for (int u = 0; u < 3; ++u)
                    o0[m * 3 + u] = *(const short8*)&qs[(mbase + m * 16 + l15) * 104 + u * 32 + kb * 8];
            gemmT_stage(o0, W + 27648, bs + 288, qs, mbase, l15, kb);
        }
        // coalesced residual RMW (wave-local rows, uint4)
        #pragma unroll
        for (int u = 0; u < 6; ++u) {
            int idx = lane + 64 * u;
            int r2 = idx / 12, c8 = idx % 12;
            ushort_t* p = X + (g0 + mbase + r2) * 96 + c8 * 8;
            float xv[8], av[8], o[8];
            unpack8(*(const uint4*)p, xv);
            unpack8(*(const uint4*)&qs[(mbase + r2) * 104 + c8 * 8], av);
            #pragma unroll
            for (int j = 0; j < 8; ++j) o[j] = xv[j] + av[j];
            *(uint4*)p = pack8(o);
        }
    }
}

// ---------------------------------------------------------------------------
// K3: fused LN->FFN->residual->conv, ZERO barriers, weights global. (256,3).
// LDS 26.6 KB -> 3 blocks/CU. grid 3456.
__global__ __launch_bounds__(256, 3) void k_ffn(
    ushort_t* __restrict__ Xf, ushort_t* __restrict__ Xb,
    const ushort_t* __restrict__ wf, const ushort_t* __restrict__ wb,
    const float* __restrict__ bsf, const float* __restrict__ bsb)
{
    __shared__ ushort_t H[128 * 104];   // 26624 B, wave-local rows
    int blk = blockIdx.x, tid = threadIdx.x;
    ushort_t* X; const ushort_t* W; const float* bs;
    if (blk < 1728) { X = Xf; W = wf; bs = bsf; }
    else            { X = Xb; W = wb; bs = bsb; blk -= 1728; }
    long g0 = (long)blk * 128;
    int lane = tid & 63, wv = tid >> 6, mbase = wv * 32;
    int l15 = lane & 15, kb = lane >> 4;
    const int ln8 = lane * 8;

    short8 xb2[6];
    #pragma unroll
    for (int m = 0; m < 2; ++m) {
        const ushort_t* px = X + (g0 + mbase + m * 16 + l15) * 96 + kb * 8;
        float f[24];
        unpack8(*(const uint4*)px, f);
        unpack8(*(const uint4*)(px + 32), f + 8);
        unpack8(*(const uint4*)(px + 64), f + 16);
        float s1 = 0.f, s2 = 0.f;
        #pragma unroll
        for (int j = 0; j < 24; ++j) { s1 += f[j]; s2 += f[j] * f[j]; }
        s1 += __shfl_xor(s1, 16); s1 += __shfl_xor(s1, 32);
        s2 += __shfl_xor(s2, 16); s2 += __shfl_xor(s2, 32);
        float mm = s1 * (1.f / 96.f);
        float rr = rsqrtf(s2 * (1.f / 96.f) - mm * mm + 1e-5f);
        #pragma unroll
        for (int j = 0; j < 24; ++j) f[j] = (f[j] - mm) * rr;
        xb2[m * 3 + 0] = pks8(f); xb2[m * 3 + 1] = pks8(f + 8); xb2[m * 3 + 2] = pks8(f + 16);
    }

    const ushort_t* W1 = W + 36864;
    const ushort_t* W2 = W + 73728;
    const ushort_t* Wc = W + 110592;
    const float* b1 = bs + 384;
    const float* b2 = bs + 768;

    f32x4 acc2[2][6];
    #pragma unroll
    for (int t = 0; t < 6; ++t) {
        float4 bv = *(const float4*)&b2[t * 16 + kb * 4];
        acc2[0][t] = {bv.x, bv.y, bv.z, bv.w};
        acc2[1][t] = {bv.x, bv.y, bv.z, bv.w};
    }
    #pragma unroll
    for (int ch = 0; ch < 4; ++ch) {
        #pragma unroll
        for (int t = 0; t < 6; ++t) {      // GEMM1-T (global W1) -> gelu -> H
            float4 bv = *(const float4*)&b1[ch * 96 + t * 16 + kb * 4];
            f32x4 A0 = {bv.x, bv.y, bv.z, bv.w};
            f32x4 A1 = {bv.x, bv.y, bv.z, bv.w};
            #pragma unroll
            for (int u = 0; u < 3; ++u) {
                short8 bw = *(const short8*)&W1[(ch * 18 + t * 3 + u) * 512 + ln8];
                A0 = MFMA16(bw, xb2[u],     A0, 0, 0, 0);
                A1 = MFMA16(bw, xb2[3 + u], A1, 0, 0, 0);
            }
            float q0[4], q1[4];
            #pragma unroll
            for (int i = 0; i < 4; ++i) { q0[i] = gelu_tanh(A0[i]); q1[i] = gelu_tanh(A1[i]); }
            *(uint2*)&H[(mbase + l15) * 104 + t * 16 + kb * 4]      = pack4(q0);
            *(uint2*)&H[(mbase + 16 + l15) * 104 + t * 16 + kb * 4] = pack4(q1);
        }
        short8 h0[3], h1[3];
        #pragma unroll
        for (int u = 0; u < 3; ++u) {
            h0[u] = *(const short8*)&H[(mbase + l15) * 104 + u * 32 + kb * 8];
            h1[u] = *(const short8*)&H[(mbase + 16 + l15) * 104 + u * 32 + kb * 8];
        }
        #pragma unroll
        for (int t = 0; t < 6; ++t) {      // GEMM2 partial (global W2)
            #pragma unroll
            for (int u = 0; u < 3; ++u) {
                short8 bw = *(const short8*)&W2[(ch * 18 + t * 3 + u) * 512 + ln8];
                acc2[0][t] = MFMA16(bw, h0[u], acc2[0][t], 0, 0, 0);
                acc2[1][t] = MFMA16(bw, h1[u], acc2[1][t], 0, 0, 0);
            }
        }
    }
    // F -> H; y = x + F (coalesced read, RMW into H) — all wave-local
    #pragma unroll
    for (int t = 0; t < 6; ++t) {
        float f0[4], f1[4];
        #pragma unroll
        for (int i = 0; i < 4; ++i) { f0[i] = acc2[0][t][i]; f1[i] = acc2[1][t][i]; }
        *(uint2*)&H[(mbase + l15) * 104 + t * 16 + kb * 4]      = pack4(f0);
        *(uint2*)&H[(mbase + 16 + l15) * 104 + t * 16 + kb * 4] = pack4(f1);
    }
    #pragma unroll
    for (int u = 0; u < 6; ++u) {
        int idx = lane + 64 * u;
        int r2 = idx / 12, c8 = idx % 12;
        float xv[8], fv[8], y[8];
        unpack8(*(const uint4*)(X + (g0 + mbase + r2) * 96 + c8 * 8), xv);
        unpack8(*(const uint4*)&H[(mbase + r2) * 104 + c8 * 8], fv);
        #pragma unroll
        for (int j = 0; j < 8; ++j) y[j] = xv[j] + fv[j];
        *(uint4*)&H[(mbase + r2) * 104 + c8 * 8] = pack8(y);
    }
    // conv (global Wc; bias cancels in IN)
    short8 y0[3], y1[3];
    #pragma unroll
    for (int u = 0; u < 3; ++u) {
        y0[u] = *(const short8*)&H[(mbase + l15) * 104 + u * 32 + kb * 8];
        y1[u] = *(const short8*)&H[(mbase + 16 + l15) * 104 + u * 32 + kb * 8];
    }
    #pragma unroll
    for (int t = 0; t < 6; ++t) {
        f32x4 A0 = {0.f, 0.f, 0.f, 0.f}, A1 = {0.f, 0.f, 0.f, 0.f};
        #pragma unroll
        for (int u = 0; u < 3; ++u) {
            short8 bw = *(const short8*)&Wc[(t * 3 + u) * 512 + ln8];
            A0 = MFMA16(bw, y0[u], A0, 0, 0, 0);
            A1 = MFMA16(bw, y1[u], A1, 0, 0, 0);
        }
        float o0[4], o1[4];
        #pragma unroll
        for (int i = 0; i < 4; ++i) { o0[i] = A0[i]; o1[i] = A1[i]; }
        *(uint2*)&H[(mbase + l15) * 104 + t * 16 + kb * 4]      = pack4(o0);
        *(uint2*)&H[(mbase + 16 + l15) * 104 + t * 16 + kb * 4] = pack4(o1);
    }
    #pragma unroll
    for (int u = 0; u < 6; ++u) {
        int idx = lane + 64 * u;
        int r2 = idx / 12, c8 = idx % 12;
        *(uint4*)(X + (g0 + mbase + r2) * 96 + c8 * 8) =
            *(const uint4*)&H[(mbase + r2) * 104 + c8 * 8];
    }
}

// ---------------------------------------------------------------------------
// K5: InstanceNorm partial sums (vectorized). grid 216, block 384.
__global__ __launch_bounds__(384) void k_instats(
    const ushort_t* __restrict__ Xf, const ushort_t* __restrict__ Xb,
    float* __restrict__ partial)
{
    __shared__ float red[2][32][96];
    int blk = blockIdx.x;
    const ushort_t* X = (blk < 108) ? Xf : Xb;
    int rem = blk % 108;
    int b = rem / 54, chunk = rem % 54;
    int tid = threadIdx.x;
    int c8 = tid % 12, slot = tid / 12;    // 32 slots
    long base = (long)b * TOK_PER_B + chunk * 2048;
    float s8[8], ss8[8];
    #pragma unroll
    for (int j = 0; j < 8; ++j) { s8[j] = 0.f; ss8[j] = 0.f; }
    for (int i = 0; i < 64; ++i) {
        long row = base + i * 32 + slot;
        float f[8];
        unpack8(*(const uint4*)&X[row * 96 + c8 * 8], f);
        #pragma unroll
        for (int j = 0; j < 8; ++j) { s8[j] += f[j]; ss8[j] += f[j] * f[j]; }
    }
    #pragma unroll
    for (int j = 0; j < 8; ++j) {
        red[0][slot][c8 * 8 + j] = s8[j];
        red[1][slot][c8 * 8 + j] = ss8[j];
    }
    __syncthreads();
    if (tid < 96) {
        float S = 0.f, SS = 0.f;
        for (int sl = 0; sl < 32; ++sl) { S += red[0][sl][tid]; SS += red[1][sl][tid]; }
        partial[((long)blockIdx.x * 96 + tid) * 2]     = S;
        partial[((long)blockIdx.x * 96 + tid) * 2 + 1] = SS;
    }
}

__global__ __launch_bounds__(384) void k_infin(
    const float* __restrict__ partial, float* __restrict__ inMR)
{
    int tid = threadIdx.x;
    int s = tid / 192, rem = tid % 192, b = rem / 96, c = rem % 96;
    float S = 0.f, SS = 0.f;
    for (int ch = 0; ch < 54; ++ch) {
        int blk = s * 108 + b * 54 + ch;
        S  += partial[(blk * 96 + c) * 2];
        SS += partial[(blk * 96 + c) * 2 + 1];
    }
    float m = S * (1.f / 110592.f);
    float var = SS * (1.f / 110592.f) - m * m;
    inMR[tid * 2] = m;
    inMR[tid * 2 + 1] = rsqrtf(var + 1e-5f);
}

// ---------------------------------------------------------------------------
// K7: IN affine + GELU + window-reverse scatter. grid 2304.
__global__ __launch_bounds__(256) void k_scatter(
    const ushort_t* __restrict__ Xf, const ushort_t* __restrict__ Xb,
    const float* __restrict__ inMR,
    const float* __restrict__ iwf, const float* __restrict__ ibf,
    const float* __restrict__ iwb, const float* __restrict__ ibb,
    float* __restrict__ out)
{
    __shared__ float tile[192 * 97];
    int blk = blockIdx.x, s = 0;
    const ushort_t* X = Xf; const float* iw = iwf; const float* ib = ibf;
    if (blk >= 1152) { s = 1; X = Xb; iw = iwb; ib = ibb; blk -= 1152; }
    int b = blk / 576, rem = blk % 576, dw = rem / 24, hw = rem % 24;
    int tid = threadIdx.x;
    long base = ((((long)b * 24 + dw) * 24 + hw) * 24) * 8;
    for (int i = tid; i < 192 * 12; i += 256) {
        int t = i / 12, c8 = i % 12;
        float f[8]; unpack8(*(const uint4*)&X[(base + t) * 96 + c8 * 8], f);
        #pragma unroll
        for (int j = 0; j < 8; ++j) tile[t * 97 + c8 * 8 + j] = f[j];
    }
    __syncthreads();
    float* o = out + (long)s * STREAM_ELEMS;
    for (int i = tid; i < 384 * 48; i += 256) {
        int r = i / 48, w = i % 48;
        int c = r >> 2, d_off = (r >> 1) & 1, h_off = r & 1;
        int t = (w >> 1) * 8 + d_off * 4 + h_off * 2 + (w & 1);
        float v = tile[t * 97 + c];
        float m  = inMR[((s * 2 + b) * 96 + c) * 2];
        float rr = inMR[((s * 2 + b) * 96 + c) * 2 + 1];
        v = (v - m) * rr * iw[c] + ib[c];
        o[((((long)b * 96 + c) * 48 + dw * 2 + d_off) * 48 + hw * 2 + h_off) * 48 + w] = gelu_erf(v);
    }
}

// ---------------------------------------------------------------------------
extern "C" void kernel_launch(void* const* d_in, const int* in_sizes, int n_in,
                              void* d_out, int out_size, void* d_ws, size_t ws_size,
                              hipStream_t stream)
{
    #define IN(i) ((const float*)d_in[i])
    ushort_t* Xf = (ushort_t*)d_ws;
    ushort_t* Xb = Xf + (long)STREAM_ELEMS;
    ushort_t* wW  = Xb + (long)STREAM_ELEMS;
    ushort_t* wWb = wW + 119808;
    float* bsf = (float*)(wWb + 119808);
    float* bsb = bsf + 864;
    float* partial = bsb + 864;            // 216*96*2 floats
    float* inMR = partial + 41472;

    k_fold<<<128, 256, 0, stream>>>(IN(6), IN(7), IN(8), IN(9), IN(12), IN(13), IN(14), IN(15), IN(16),
                                    IN(2), IN(3), IN(22), IN(23), IN(10), IN(11), wW, bsf);
    k_fold<<<128, 256, 0, stream>>>(IN(24), IN(25), IN(26), IN(27), IN(30), IN(31), IN(32), IN(33), IN(34),
                                    IN(20), IN(21), IN(4), IN(5), IN(28), IN(29), wWb, bsb);

    k_gather<<<2304, 256, 0, stream>>>(IN(0), IN(1), Xf, Xb);

    k_attn<<<1728, 256, 0, stream>>>(Xf, Xb, wW, wWb, bsf, bsb);

    k_ffn<<<3456, 256, 0, stream>>>(Xf, Xb, wW, wWb, bsf, bsb);

    k_instats<<<216, 384, 0, stream>>>(Xf, Xb, partial);
    k_infin<<<1, 384, 0, stream>>>(partial, inMR);

    k_scatter<<<2304, 256, 0, stream>>>(Xf, Xb, inMR,
                                        IN(18), IN(19), IN(36), IN(37),
                                        (float*)d_out);
    #undef IN
}

// Round 18
// 528.556 us; speedup vs baseline: 1.2483x; 1.2483x over previous
//
#include <hip/hip_runtime.h>
#include <hip/hip_bf16.h>

// LocalCrossAttentionBlock3D — R18: R16 base (best, 532.7us) + k_ffn keeps raw-X
// fragments in registers: residual y = xraw + F computed in-reg, deleting the
// X re-read + H RMW pass. B=2,C=96,D=H=W=48,NH=4,dh=24,HID=384.

#define G_TOK 221184
#define TOK_PER_B 110592
#define STREAM_ELEMS 21233664  // G_TOK*96

typedef __attribute__((ext_vector_type(8))) short short8;
typedef __attribute__((ext_vector_type(4))) float f32x4;
typedef unsigned short ushort_t;
typedef unsigned int uint_t;

#define MFMA16 __builtin_amdgcn_mfma_f32_16x16x32_bf16

__device__ __forceinline__ float gelu_erf(float x) {
    return 0.5f * x * (1.0f + erff(x * 0.70710678118654752f));
}
__device__ __forceinline__ float gelu_tanh(float x) {
    float u = x * (1.5957691216f + 0.0713548163f * x * x);
    return x / (1.0f + __expf(-u));
}
__device__ __forceinline__ ushort_t bfb(float f) {
    __hip_bfloat16 h = __float2bfloat16(f);
    return *reinterpret_cast<ushort_t*>(&h);
}
__device__ __forceinline__ void unpack8(uint4 v, float* o) {
    o[0] = __uint_as_float(v.x << 16); o[1] = __uint_as_float(v.x & 0xffff0000u);
    o[2] = __uint_as_float(v.y << 16); o[3] = __uint_as_float(v.y & 0xffff0000u);
    o[4] = __uint_as_float(v.z << 16); o[5] = __uint_as_float(v.z & 0xffff0000u);
    o[6] = __uint_as_float(v.w << 16); o[7] = __uint_as_float(v.w & 0xffff0000u);
}
__device__ __forceinline__ void unpack8s(short8 v, float* o) {
    unpack8(*(uint4*)&v, o);
}
__device__ __forceinline__ uint4 pack8(const float* f) {
    uint4 v;
    v.x = (uint_t)bfb(f[0]) | ((uint_t)bfb(f[1]) << 16);
    v.y = (uint_t)bfb(f[2]) | ((uint_t)bfb(f[3]) << 16);
    v.z = (uint_t)bfb(f[4]) | ((uint_t)bfb(f[5]) << 16);
    v.w = (uint_t)bfb(f[6]) | ((uint_t)bfb(f[7]) << 16);
    return v;
}
__device__ __forceinline__ uint2 pack4(const float* f) {
    uint2 v;
    v.x = (uint_t)bfb(f[0]) | ((uint_t)bfb(f[1]) << 16);
    v.y = (uint_t)bfb(f[2]) | ((uint_t)bfb(f[3]) << 16);
    return v;
}
__device__ __forceinline__ short8 pks8(const float* f) {
    short8 r;
    #pragma unroll
    for (int j = 0; j < 8; ++j) r[j] = (short)bfb(f[j]);
    return r;
}

// Async global->LDS stage: n16 uint4 elems, linear both sides.
__device__ __forceinline__ void stageAsync(ushort_t* dst, const ushort_t* src, int tid, int n16) {
    int wv = tid >> 6;
    #pragma unroll
    for (int i = 0; i < 2304; i += 256) {
        if (i >= n16) break;
        int idx = tid + i;
        if (idx < n16) {
            __builtin_amdgcn_global_load_lds(
                (const __attribute__((address_space(1))) uint_t*)((const uint4*)src + idx),
                (__attribute__((address_space(3))) uint_t*)(dst + (i + wv * 64) * 8),
                16, 0, 0);
        }
    }
}

// ---------------------------------------------------------------------------
// K0: fold LN affines into LANE-MAJOR fragment bf16 weights.
__global__ __launch_bounds__(256) void k_fold(
    const float* __restrict__ Wi, const float* __restrict__ bi,
    const float* __restrict__ Wo, const float* __restrict__ bo,
    const float* __restrict__ W1, const float* __restrict__ b1,
    const float* __restrict__ W2, const float* __restrict__ b2,
    const float* __restrict__ Wc,
    const float* __restrict__ qnw, const float* __restrict__ qnb,
    const float* __restrict__ kvw, const float* __restrict__ kvb,
    const float* __restrict__ fnw, const float* __restrict__ fnb,
    ushort_t* __restrict__ w, float* __restrict__ bs)
{
    const float scale = 0.20412414523193150f;  // 1/sqrt(24)
    int tid0 = blockIdx.x * 256 + threadIdx.x;
    int nth = gridDim.x * 256;
    for (int o = tid0; o < 120672; o += nth) {
        if (o < 36864) {
            int blkid = o / 9216, oo = o % 9216;
            int e = oo & 7, ln = (oo >> 3) & 63, g = oo >> 9;
            int t = g / 3, u = g % 3, l15 = ln & 15, kb = ln >> 4;
            int c = t * 16 + l15, k = u * 32 + kb * 8 + e;
            float v;
            if (blkid == 0)      v = Wi[c * 96 + k] * qnw[k] * scale;
            else if (blkid == 1) v = Wi[(96 + c) * 96 + k] * kvw[k];
            else if (blkid == 2) v = Wi[(192 + c) * 96 + k] * kvw[k];
            else                 v = Wo[c * 96 + k];
            w[o] = bfb(v);
        } else if (o < 110592) {
            int oo = o - 36864; int half = oo / 36864; oo %= 36864;
            int e = oo & 7, ln = (oo >> 3) & 63, g = oo >> 9;
            int ch = g / 18, r = g % 18, tt = r / 3, u = r % 3;
            int l15 = ln & 15, kb = ln >> 4;
            float v;
            if (half == 0) {
                int c = ch * 96 + tt * 16 + l15, k = u * 32 + kb * 8 + e;
                v = W1[c * 96 + k] * fnw[k];
            } else {
                int c = tt * 16 + l15, k = ch * 96 + u * 32 + kb * 8 + e;
                v = W2[c * 384 + k];
            }
            w[o] = bfb(v);
        } else if (o < 119808) {
            int oo = o - 110592;
            int e = oo & 7, ln = (oo >> 3) & 63, g = oo >> 9;
            int t = g / 3, u = g % 3, l15 = ln & 15, kb = ln >> 4;
            w[o] = bfb(Wc[(t * 16 + l15) * 96 + u * 32 + kb * 8 + e]);
        } else {
            int x = o - 119808;
            if (x < 96) {
                float s = bi[x];
                #pragma unroll 4
                for (int k = 0; k < 96; ++k) s += qnb[k] * Wi[x * 96 + k];
                bs[x] = s * scale;
            } else if (x < 192) {
                int c = x - 96; float s = bi[96 + c];
                #pragma unroll 4
                for (int k = 0; k < 96; ++k) s += kvb[k] * Wi[(96 + c) * 96 + k];
                bs[x] = s;
            } else if (x < 288) {
                int c = x - 192; float s = bi[192 + c];
                #pragma unroll 4
                for (int k = 0; k < 96; ++k) s += kvb[k] * Wi[(192 + c) * 96 + k];
                bs[x] = s;
            } else if (x < 384) {
                bs[x] = bo[x - 288];
            } else if (x < 768) {
                int c = x - 384; float s = b1[c];
                #pragma unroll 4
                for (int k = 0; k < 96; ++k) s += fnb[k] * W1[c * 96 + k];
                bs[x] = s;
            } else {
                bs[x] = b2[x - 768];
            }
        }
    }
}

// ---------------------------------------------------------------------------
// K1: gather [B,C,D,H,W] f32 -> token-major bf16 X[G,96].
__global__ __launch_bounds__(256) void k_gather(
    const float* __restrict__ srcf, const float* __restrict__ srcb,
    ushort_t* __restrict__ Xf, ushort_t* __restrict__ Xb)
{
    __shared__ float tile[192 * 97];
    int blk = blockIdx.x;
    const float* src; ushort_t* X;
    if (blk < 1152) { src = srcf; X = Xf; }
    else            { src = srcb; X = Xb; blk -= 1152; }
    int b = blk / 576, rem = blk % 576, dw = rem / 24, hw = rem % 24;
    int tid = threadIdx.x;
    for (int i = tid; i < 384 * 48; i += 256) {
        int r = i / 48, w = i % 48;
        int c = r >> 2, d_off = (r >> 1) & 1, h_off = r & 1;
        float v = src[((((long)b * 96 + c) * 48 + dw * 2 + d_off) * 48 + hw * 2 + h_off) * 48 + w];
        int t = (w >> 1) * 8 + d_off * 4 + h_off * 2 + (w & 1);
        tile[t * 97 + c] = v;
    }
    __syncthreads();
    long base = ((((long)b * 24 + dw) * 24 + hw) * 24) * 8;
    for (int i = tid; i < 192 * 12; i += 256) {
        int t = i / 12, c8 = i % 12;
        *(uint4*)&X[(base + t) * 96 + c8 * 8] = pack8(&tile[t * 97 + c8 * 8]);
    }
}

// ---------------------------------------------------------------------------
// Transposed wave-local GEMM (lane-major frags): D^T = W(A) x X(B).
__device__ __forceinline__ void gemmT_stage(
    const short8* xb2, const ushort_t* __restrict__ W,
    const float* __restrict__ bias, ushort_t* outs,
    int mbase, int l15, int kb)
{
    const int ln8 = (kb * 16 + l15) * 8;
    #pragma unroll
    for (int t = 0; t < 6; ++t) {
        float4 bv = *(const float4*)&bias[t * 16 + kb * 4];
        f32x4 A0 = {bv.x, bv.y, bv.z, bv.w};
        f32x4 A1 = {bv.x, bv.y, bv.z, bv.w};
        #pragma unroll
        for (int u = 0; u < 3; ++u) {
            short8 bw = *(const short8*)&W[(t * 3 + u) * 512 + ln8];
            A0 = MFMA16(bw, xb2[u],     A0, 0, 0, 0);
            A1 = MFMA16(bw, xb2[3 + u], A1, 0, 0, 0);
        }
        float f0[4], f1[4];
        #pragma unroll
        for (int i = 0; i < 4; ++i) { f0[i] = A0[i]; f1[i] = A1[i]; }
        *(uint2*)&outs[(mbase + l15) * 104 + t * 16 + kb * 4]      = pack4(f0);
        *(uint2*)&outs[(mbase + 16 + l15) * 104 + t * 16 + kb * 4] = pack4(f1);
    }
}

// K2: fused cross-MHA. Wq from global, Wk/Wv/Wo async-staged. (256,2). grid 1728.
__global__ __launch_bounds__(256, 2) void k_attn(
    ushort_t* __restrict__ Xf, ushort_t* __restrict__ Xb,
    const ushort_t* __restrict__ wf, const ushort_t* __restrict__ wb,
    const float* __restrict__ bsf, const float* __restrict__ bsb)
{
    __shared__ ushort_t qs[128 * 104];
    __shared__ ushort_t kv[128 * 104];
    __shared__ ushort_t WB[9216];
    int tid = threadIdx.x, lane = tid & 63, wv = tid >> 6, mbase = wv * 32;
    int l15 = lane & 15, kb = lane >> 4;
    long g0 = (long)blockIdx.x * 128;

    short8 fr[2][6];
    #pragma unroll
    for (int s = 0; s < 2; ++s) {
        #pragma unroll
        for (int m = 0; m < 2; ++m) {
            const ushort_t* px = (s ? Xb : Xf) + (g0 + mbase + m * 16 + l15) * 96 + kb * 8;
            float f[24];
            unpack8(*(const uint4*)px, f);
            unpack8(*(const uint4*)(px + 32), f + 8);
            unpack8(*(const uint4*)(px + 64), f + 16);
            float s1 = 0.f, s2 = 0.f;
            #pragma unroll
            for (int j = 0; j < 24; ++j) { s1 += f[j]; s2 += f[j] * f[j]; }
            s1 += __shfl_xor(s1, 16); s1 += __shfl_xor(s1, 32);
            s2 += __shfl_xor(s2, 16); s2 += __shfl_xor(s2, 32);
            float mm = s1 * (1.f / 96.f);
            float rr = rsqrtf(s2 * (1.f / 96.f) - mm * mm + 1e-5f);
            #pragma unroll
            for (int j = 0; j < 24; ++j) f[j] = (f[j] - mm) * rr;
            fr[s][m * 3 + 0] = pks8(f);
            fr[s][m * 3 + 1] = pks8(f + 8);
            fr[s][m * 3 + 2] = pks8(f + 16);
        }
    }

    #pragma unroll
    for (int dir = 0; dir < 2; ++dir) {
        const ushort_t* W = dir ? wb : wf;
        const float* bs = dir ? bsb : bsf;
        ushort_t* X = dir ? Xb : Xf;

        // async-stage Wk while Q-GEMM reads Wq direct from global
        stageAsync(WB, W + 9216, tid, 1152);
        gemmT_stage(fr[dir], W, bs, qs, mbase, l15, kb);                 // Q (global Wq)
        __syncthreads();
        gemmT_stage(fr[dir ^ 1], WB, bs + 96, kv, mbase, l15, kb);       // K (LDS)

        // scores — qf[24] live, kf transient 8-wide
        float sc[2][8], inv[2];
        #pragma unroll
        for (int it = 0; it < 2; ++it) {
            int idx = lane + 64 * it;
            int win = (idx >> 5) & 3, hd = (idx >> 3) & 3, q8 = idx & 7;
            int tq = mbase + win * 8 + q8, ko = hd * 24;
            float qf[24];
            #pragma unroll
            for (int u = 0; u < 3; ++u)
                unpack8(*(const uint4*)&qs[tq * 104 + ko + u * 8], qf + u * 8);
            float mx = -1e30f;
            #pragma unroll
            for (int j = 0; j < 8; ++j) {
                float s = 0.f;
                #pragma unroll
                for (int u = 0; u < 3; ++u) {
                    float kf[8];
                    unpack8(*(const uint4*)&kv[(mbase + win * 8 + j) * 104 + ko + u * 8], kf);
                    #pragma unroll
                    for (int d = 0; d < 8; ++d) s += qf[u * 8 + d] * kf[d];
                }
                sc[it][j] = s; mx = fmaxf(mx, s);
            }
            float sum = 0.f;
            #pragma unroll
            for (int j = 0; j < 8; ++j) { sc[it][j] = __expf(sc[it][j] - mx); sum += sc[it][j]; }
            inv[it] = 1.f / sum;
        }
        __syncthreads();
        stageAsync(WB, W + 18432, tid, 1152);
        __syncthreads();
        gemmT_stage(fr[dir ^ 1], WB, bs + 192, kv, mbase, l15, kb);      // V over K

        // O = P.V -> qs, per-u 8-wide accumulation
        #pragma unroll
        for (int it = 0; it < 2; ++it) {
            int idx = lane + 64 * it;
            int win = (idx >> 5) & 3, hd = (idx >> 3) & 3, q8 = idx & 7;
            int tq = mbase + win * 8 + q8, ko = hd * 24;
            #pragma unroll
            for (int u = 0; u < 3; ++u) {
                float of8[8];
                #pragma unroll
                for (int d = 0; d < 8; ++d) of8[d] = 0.f;
                #pragma unroll
                for (int j = 0; j < 8; ++j) {
                    float vf[8];
                    unpack8(*(const uint4*)&kv[(mbase + win * 8 + j) * 104 + ko + u * 8], vf);
                    #pragma unroll
                    for (int d = 0; d < 8; ++d) of8[d] += sc[it][j] * vf[d];
                }
                #pragma unroll
                for (int d = 0; d < 8; ++d) of8[d] *= inv[it];
                *(uint4*)&qs[tq * 104 + ko + u * 8] = pack8(of8);
            }
        }
        __syncthreads();
        stageAsync(WB, W + 27648, tid, 1152);
        __syncthreads();
        // out-proj (transposed): frags from qs, D staged back into qs
        {
            short8 o0[6];
            #pragma unroll
            for (int m = 0; m < 2; ++m)
                #pragma unroll
                for (int u = 0; u < 3; ++u)
                    o0[m * 3 + u] = *(const short8*)&qs[(mbase + m * 16 + l15) * 104 + u * 32 + kb * 8];
            gemmT_stage(o0, WB, bs + 288, qs, mbase, l15, kb);
        }
        // coalesced residual RMW (wave-local rows, uint4)
        #pragma unroll
        for (int u = 0; u < 6; ++u) {
            int idx = lane + 64 * u;
            int r2 = idx / 12, c8 = idx % 12;
            ushort_t* p = X + (g0 + mbase + r2) * 96 + c8 * 8;
            float xv[8], av[8], o[8];
            unpack8(*(const uint4*)p, xv);
            unpack8(*(const uint4*)&qs[(mbase + r2) * 104 + c8 * 8], av);
            #pragma unroll
            for (int j = 0; j < 8; ++j) o[j] = xv[j] + av[j];
            *(uint4*)p = pack8(o);
        }
        __syncthreads();   // WB reuse by next dir
    }
}

// ---------------------------------------------------------------------------
// K3: fused LN->FFN->residual->conv; async co-staged W1/W2; raw-X frags kept
// in registers -> in-reg residual. (256,2). grid 3456.
__global__ __launch_bounds__(256, 2) void k_ffn(
    ushort_t* __restrict__ Xf, ushort_t* __restrict__ Xb,
    const ushort_t* __restrict__ wf, const ushort_t* __restrict__ wb,
    const float* __restrict__ bsf, const float* __restrict__ bsb)
{
    __shared__ ushort_t H[128 * 104];   // 26624 B
    __shared__ ushort_t WB[18432];      // 36864 B
    int blk = blockIdx.x, tid = threadIdx.x;
    ushort_t* X; const ushort_t* W; const float* bs;
    if (blk < 1728) { X = Xf; W = wf; bs = bsf; }
    else            { X = Xb; W = wb; bs = bsb; blk -= 1728; }
    long g0 = (long)blk * 128;
    int lane = tid & 63, wv = tid >> 6, mbase = wv * 32;
    int l15 = lane & 15, kb = lane >> 4;
    const int ln8 = lane * 8;

    // prefetch ch0 weights while computing LN
    stageAsync(WB, W + 36864, tid, 1152);           // W1[0]
    stageAsync(WB + 9216, W + 73728, tid, 1152);    // W2[0]

    short8 xraw[6], xb2[6];
    #pragma unroll
    for (int m = 0; m < 2; ++m) {
        const ushort_t* px = X + (g0 + mbase + m * 16 + l15) * 96 + kb * 8;
        uint4 v0 = *(const uint4*)px;
        uint4 v1 = *(const uint4*)(px + 32);
        uint4 v2 = *(const uint4*)(px + 64);
        xraw[m * 3 + 0] = *(short8*)&v0;
        xraw[m * 3 + 1] = *(short8*)&v1;
        xraw[m * 3 + 2] = *(short8*)&v2;
        float f[24];
        unpack8(v0, f); unpack8(v1, f + 8); unpack8(v2, f + 16);
        float s1 = 0.f, s2 = 0.f;
        #pragma unroll
        for (int j = 0; j < 24; ++j) { s1 += f[j]; s2 += f[j] * f[j]; }
        s1 += __shfl_xor(s1, 16); s1 += __shfl_xor(s1, 32);
        s2 += __shfl_xor(s2, 16); s2 += __shfl_xor(s2, 32);
        float mm = s1 * (1.f / 96.f);
        float rr = rsqrtf(s2 * (1.f / 96.f) - mm * mm + 1e-5f);
        #pragma unroll
        for (int j = 0; j < 24; ++j) f[j] = (f[j] - mm) * rr;
        xb2[m * 3 + 0] = pks8(f); xb2[m * 3 + 1] = pks8(f + 8); xb2[m * 3 + 2] = pks8(f + 16);
    }

    const ushort_t* W1 = W + 36864;
    const ushort_t* W2 = W + 73728;
    const ushort_t* Wc = W + 110592;
    const float* b1 = bs + 384;
    const float* b2 = bs + 768;

    f32x4 acc2[2][6];
    #pragma unroll
    for (int t = 0; t < 6; ++t) {
        float4 bv = *(const float4*)&b2[t * 16 + kb * 4];
        acc2[0][t] = {bv.x, bv.y, bv.z, bv.w};
        acc2[1][t] = {bv.x, bv.y, bv.z, bv.w};
    }
    for (int ch = 0; ch < 4; ++ch) {
        __syncthreads();   // current ch weights landed
        #pragma unroll
        for (int t = 0; t < 6; ++t) {      // GEMM1-T from WB -> gelu -> H (b64)
            float4 bv = *(const float4*)&b1[ch * 96 + t * 16 + kb * 4];
            f32x4 A0 = {bv.x, bv.y, bv.z, bv.w};
            f32x4 A1 = {bv.x, bv.y, bv.z, bv.w};
            #pragma unroll
            for (int u = 0; u < 3; ++u) {
                short8 bw = *(const short8*)&WB[(t * 3 + u) * 512 + ln8];
                A0 = MFMA16(bw, xb2[u],     A0, 0, 0, 0);
                A1 = MFMA16(bw, xb2[3 + u], A1, 0, 0, 0);
            }
            float q0[4], q1[4];
            #pragma unroll
            for (int i = 0; i < 4; ++i) { q0[i] = gelu_tanh(A0[i]); q1[i] = gelu_tanh(A1[i]); }
            *(uint2*)&H[(mbase + l15) * 104 + t * 16 + kb * 4]      = pack4(q0);
            *(uint2*)&H[(mbase + 16 + l15) * 104 + t * 16 + kb * 4] = pack4(q1);
        }
        short8 h0[3], h1[3];
        #pragma unroll
        for (int u = 0; u < 3; ++u) {
            h0[u] = *(const short8*)&H[(mbase + l15) * 104 + u * 32 + kb * 8];
            h1[u] = *(const short8*)&H[(mbase + 16 + l15) * 104 + u * 32 + kb * 8];
        }
        #pragma unroll
        for (int t = 0; t < 6; ++t) {      // GEMM2 partial from WB[9216+]
            #pragma unroll
            for (int u = 0; u < 3; ++u) {
                short8 bw = *(const short8*)&WB[9216 + (t * 3 + u) * 512 + ln8];
                acc2[0][t] = MFMA16(bw, h0[u], acc2[0][t], 0, 0, 0);
                acc2[1][t] = MFMA16(bw, h1[u], acc2[1][t], 0, 0, 0);
            }
        }
        __syncthreads();   // all waves done reading WB
        if (ch < 3) {      // prefetch next ch
            stageAsync(WB, W1 + (ch + 1) * 9216, tid, 1152);
            stageAsync(WB + 9216, W2 + (ch + 1) * 9216, tid, 1152);
        } else {
            stageAsync(WB, Wc, tid, 1152);
        }
    }
    // F -> H (b64, wave-local)
    #pragma unroll
    for (int t = 0; t < 6; ++t) {
        float f0[4], f1[4];
        #pragma unroll
        for (int i = 0; i < 4; ++i) { f0[i] = acc2[0][t][i]; f1[i] = acc2[1][t][i]; }
        *(uint2*)&H[(mbase + l15) * 104 + t * 16 + kb * 4]      = pack4(f0);
        *(uint2*)&H[(mbase + 16 + l15) * 104 + t * 16 + kb * 4] = pack4(f1);
    }
    // y = xraw + F, fully in registers (F frags read back from H, wave-local)
    short8 yfr[6];
    #pragma unroll
    for (int m = 0; m < 2; ++m)
        #pragma unroll
        for (int u = 0; u < 3; ++u) {
            short8 F8 = *(const short8*)&H[(mbase + m * 16 + l15) * 104 + u * 32 + kb * 8];
            float xa[8], fa[8];
            unpack8s(xraw[m * 3 + u], xa);
            unpack8s(F8, fa);
            #pragma unroll
            for (int j = 0; j < 8; ++j) xa[j] += fa[j];
            yfr[m * 3 + u] = pks8(xa);
        }
    __syncthreads();   // Wc landed
    // conv from WB (bias cancels in IN): y frags in regs -> conv out -> H
    #pragma unroll
    for (int t = 0; t < 6; ++t) {
        f32x4 A0 = {0.f, 0.f, 0.f, 0.f}, A1 = {0.f, 0.f, 0.f, 0.f};
        #pragma unroll
        for (int u = 0; u < 3; ++u) {
            short8 bw = *(const short8*)&WB[(t * 3 + u) * 512 + ln8];
            A0 = MFMA16(bw, yfr[u],     A0, 0, 0, 0);
            A1 = MFMA16(bw, yfr[3 + u], A1, 0, 0, 0);
        }
        float o0[4], o1[4];
        #pragma unroll
        for (int i = 0; i < 4; ++i) { o0[i] = A0[i]; o1[i] = A1[i]; }
        *(uint2*)&H[(mbase + l15) * 104 + t * 16 + kb * 4]      = pack4(o0);
        *(uint2*)&H[(mbase + 16 + l15) * 104 + t * 16 + kb * 4] = pack4(o1);
    }
    // coalesced store X <- H
    #pragma unroll
    for (int u = 0; u < 6; ++u) {
        int idx = lane + 64 * u;
        int r2 = idx / 12, c8 = idx % 12;
        *(uint4*)(X + (g0 + mbase + r2) * 96 + c8 * 8) =
            *(const uint4*)&H[(mbase + r2) * 104 + c8 * 8];
    }
}

// ---------------------------------------------------------------------------
// K5: InstanceNorm partial sums (vectorized). grid 216, block 384.
__global__ __launch_bounds__(384) void k_instats(
    const ushort_t* __restrict__ Xf, const ushort_t* __restrict__ Xb,
    float* __restrict__ partial)
{
    __shared__ float red[2][32][96];
    int blk = blockIdx.x;
    const ushort_t* X = (blk < 108) ? Xf : Xb;
    int rem = blk % 108;
    int b = rem / 54, chunk = rem % 54;
    int tid = threadIdx.x;
    int c8 = tid % 12, slot = tid / 12;    // 32 slots
    long base = (long)b * TOK_PER_B + chunk * 2048;
    float s8[8], ss8[8];
    #pragma unroll
    for (int j = 0; j < 8; ++j) { s8[j] = 0.f; ss8[j] = 0.f; }
    for (int i = 0; i < 64; ++i) {
        long row = base + i * 32 + slot;
        float f[8];
        unpack8(*(const uint4*)&X[row * 96 + c8 * 8], f);
        #pragma unroll
        for (int j = 0; j < 8; ++j) { s8[j] += f[j]; ss8[j] += f[j] * f[j]; }
    }
    #pragma unroll
    for (int j = 0; j < 8; ++j) {
        red[0][slot][c8 * 8 + j] = s8[j];
        red[1][slot][c8 * 8 + j] = ss8[j];
    }
    __syncthreads();
    if (tid < 96) {
        float S = 0.f, SS = 0.f;
        for (int sl = 0; sl < 32; ++sl) { S += red[0][sl][tid]; SS += red[1][sl][tid]; }
        partial[((long)blockIdx.x * 96 + tid) * 2]     = S;
        partial[((long)blockIdx.x * 96 + tid) * 2 + 1] = SS;
    }
}

__global__ __launch_bounds__(384) void k_infin(
    const float* __restrict__ partial, float* __restrict__ inMR)
{
    int tid = threadIdx.x;
    int s = tid / 192, rem = tid % 192, b = rem / 96, c = rem % 96;
    float S = 0.f, SS = 0.f;
    for (int ch = 0; ch < 54; ++ch) {
        int blk = s * 108 + b * 54 + ch;
        S  += partial[(blk * 96 + c) * 2];
        SS += partial[(blk * 96 + c) * 2 + 1];
    }
    float m = S * (1.f / 110592.f);
    float var = SS * (1.f / 110592.f) - m * m;
    inMR[tid * 2] = m;
    inMR[tid * 2 + 1] = rsqrtf(var + 1e-5f);
}

// ---------------------------------------------------------------------------
// K7: IN affine + GELU + window-reverse scatter. grid 2304.
__global__ __launch_bounds__(256) void k_scatter(
    const ushort_t* __restrict__ Xf, const ushort_t* __restrict__ Xb,
    const float* __restrict__ inMR,
    const float* __restrict__ iwf, const float* __restrict__ ibf,
    const float* __restrict__ iwb, const float* __restrict__ ibb,
    float* __restrict__ out)
{
    __shared__ float tile[192 * 97];
    int blk = blockIdx.x, s = 0;
    const ushort_t* X = Xf; const float* iw = iwf; const float* ib = ibf;
    if (blk >= 1152) { s = 1; X = Xb; iw = iwb; ib = ibb; blk -= 1152; }
    int b = blk / 576, rem = blk % 576, dw = rem / 24, hw = rem % 24;
    int tid = threadIdx.x;
    long base = ((((long)b * 24 + dw) * 24 + hw) * 24) * 8;
    for (int i = tid; i < 192 * 12; i += 256) {
        int t = i / 12, c8 = i % 12;
        float f[8]; unpack8(*(const uint4*)&X[(base + t) * 96 + c8 * 8], f);
        #pragma unroll
        for (int j = 0; j < 8; ++j) tile[t * 97 + c8 * 8 + j] = f[j];
    }
    __syncthreads();
    float* o = out + (long)s * STREAM_ELEMS;
    for (int i = tid; i < 384 * 48; i += 256) {
        int r = i / 48, w = i % 48;
        int c = r >> 2, d_off = (r >> 1) & 1, h_off = r & 1;
        int t = (w >> 1) * 8 + d_off * 4 + h_off * 2 + (w & 1);
        float v = tile[t * 97 + c];
        float m  = inMR[((s * 2 + b) * 96 + c) * 2];
        float rr = inMR[((s * 2 + b) * 96 + c) * 2 + 1];
        v = (v - m) * rr * iw[c] + ib[c];
        o[((((long)b * 96 + c) * 48 + dw * 2 + d_off) * 48 + hw * 2 + h_off) * 48 + w] = gelu_erf(v);
    }
}

// ---------------------------------------------------------------------------
extern "C" void kernel_launch(void* const* d_in, const int* in_sizes, int n_in,
                              void* d_out, int out_size, void* d_ws, size_t ws_size,
                              hipStream_t stream)
{
    #define IN(i) ((const float*)d_in[i])
    ushort_t* Xf = (ushort_t*)d_ws;
    ushort_t* Xb = Xf + (long)STREAM_ELEMS;
    ushort_t* wW  = Xb + (long)STREAM_ELEMS;
    ushort_t* wWb = wW + 119808;
    float* bsf = (float*)(wWb + 119808);
    float* bsb = bsf + 864;
    float* partial = bsb + 864;            // 216*96*2 floats
    float* inMR = partial + 41472;

    k_fold<<<128, 256, 0, stream>>>(IN(6), IN(7), IN(8), IN(9), IN(12), IN(13), IN(14), IN(15), IN(16),
                                    IN(2), IN(3), IN(22), IN(23), IN(10), IN(11), wW, bsf);
    k_fold<<<128, 256, 0, stream>>>(IN(24), IN(25), IN(26), IN(27), IN(30), IN(31), IN(32), IN(33), IN(34),
                                    IN(20), IN(21), IN(4), IN(5), IN(28), IN(29), wWb, bsb);

    k_gather<<<2304, 256, 0, stream>>>(IN(0), IN(1), Xf, Xb);

    k_attn<<<1728, 256, 0, stream>>>(Xf, Xb, wW, wWb, bsf, bsb);

    k_ffn<<<3456, 256, 0, stream>>>(Xf, Xb, wW, wWb, bsf, bsb);

    k_instats<<<216, 384, 0, stream>>>(Xf, Xb, partial);
    k_infin<<<1, 384, 0, stream>>>(partial, inMR);

    k_scatter<<<2304, 256, 0, stream>>>(Xf, Xb, inMR,
                                        IN(18), IN(19), IN(36), IN(37),
                                        (float*)d_out);
    #undef IN
}